// Round 7
// baseline (31.838 us; speedup 1.0000x reference)
//
#include <hip/hip_runtime.h>

#define NB 8
#define NC 4
#define NH 256
#define NW 256
#define HW (NH * NW)      // 65536
#define CHW (NC * HW)     // 262144
#define INFV 1e10f
#define TH 4                              // output rows per block
#define HP 264                            // padded h extent: 4 + 256 + 4
#define MAIN_BLOCKS (NB * (NH / TH))      // 512

// ---------------------------------------------------------------------------
// K1: EDT pass 1 along W (ballot + clz/ffs), restructured to 4 rows/block so
// the output can be written TRANSPOSED: Dt[b][c][w][4+h] u16, with 4 sentinel
// (65535) rows padded at both ends of h. 65535 = class absent in row
// (reference: 1e10); else exact squared distance <= 65025.
// Grid: 512 blocks x 256 threads; thread = column, block = 4 image rows.
// ---------------------------------------------------------------------------
__global__ __launch_bounds__(256) void k_edt_w(const int* __restrict__ tgt,
                                               unsigned short* __restrict__ Dt) {
    int blk  = blockIdx.x;          // b*64 + tile
    int b    = blk >> 6;
    int tile = blk & 63;
    int h0   = tile * TH;
    int t    = threadIdx.x;         // column
    int wv   = t >> 6;
    int ln   = t & 63;

    __shared__ unsigned long long mk[TH][NC][4];

    int tv[TH];
    #pragma unroll
    for (int r = 0; r < TH; ++r)
        tv[r] = tgt[((size_t)b * NH + h0 + r) * NW + t];

    #pragma unroll
    for (int r = 0; r < TH; ++r) {
        #pragma unroll
        for (int c = 0; c < NC; ++c) {
            unsigned long long m = __ballot(tv[r] == c);
            if (ln == 0) mk[r][c][wv] = m;
        }
    }
    __syncthreads();

    unsigned long long le = (ln == 63) ? ~0ull : ((1ull << (ln + 1)) - 1ull);
    unsigned long long ge = ~0ull << ln;

    #pragma unroll
    for (int c = 0; c < NC; ++c) {
        unsigned short q[TH];
        #pragma unroll
        for (int r = 0; r < TH; ++r) {
            int jl = -1000;
            #pragma unroll
            for (int k = 0; k < 4; ++k) {
                unsigned long long x = mk[r][c][k];
                x = (k > wv) ? 0ull : ((k == wv) ? (x & le) : x);
                if (x) jl = k * 64 + 63 - __clzll((long long)x);
            }
            int jr = 1000;
            #pragma unroll
            for (int k = 3; k >= 0; --k) {
                unsigned long long x = mk[r][c][k];
                x = (k < wv) ? 0ull : ((k == wv) ? (x & ge) : x);
                if (x) jr = k * 64 + __ffsll((unsigned long long)x) - 1;
            }
            int dd = min(t - jl, jr - t);
            q[r] = (dd > 255) ? (unsigned short)65535
                              : (unsigned short)(dd * dd);
        }
        // pack 4 rows -> one 8B store (byte offset (..)*528 + 8 + 2*h0, 8B-aligned)
        uint2 pk;
        pk.x = (unsigned)q[0] | ((unsigned)q[1] << 16);
        pk.y = (unsigned)q[2] | ((unsigned)q[3] << 16);
        unsigned short* colp = Dt + ((size_t)(b * NC + c) * NW + t) * HP;
        *(uint2*)(colp + 4 + h0) = pk;
        if (tile == 0) {                    // top sentinel rows (h = -4..-1)
            uint2 s; s.x = 0xFFFFFFFFu; s.y = 0xFFFFFFFFu;
            *(uint2*)(colp) = s;
        }
        if (tile == 63) {                   // bottom sentinel rows (h = 256..259)
            uint2 s; s.x = 0xFFFFFFFFu; s.y = 0xFFFFFFFFu;
            *(uint2*)(colp + 260) = s;
        }
    }
}

// ---------------------------------------------------------------------------
// softmax of the 4 channel logits at pixel offset hw of batch-base pred_b.
// ---------------------------------------------------------------------------
__device__ __forceinline__ void softmax4(const float* __restrict__ pred_b,
                                         int hw, float o[NC]) {
    float x0 = pred_b[hw];
    float x1 = pred_b[hw + HW];
    float x2 = pred_b[hw + 2 * HW];
    float x3 = pred_b[hw + 3 * HW];
    float m  = fmaxf(fmaxf(x0, x1), fmaxf(x2, x3));
    float e0 = __expf(x0 - m);
    float e1 = __expf(x1 - m);
    float e2 = __expf(x2 - m);
    float e3 = __expf(x3 - m);
    float inv = 1.0f / (e0 + e1 + e2 + e3);
    o[0] = e0 * inv; o[1] = e1 * inv; o[2] = e2 * inv; o[3] = e3 * inv;
}

// ---------------------------------------------------------------------------
// K2: fused kernel. Block = 256 threads (w) x TH=4 output rows.
//  - D window: 12 contiguous u16/ch from transposed Dt -> 3 dwordx2 loads/ch
//    (12 VMEM total, was 48 scalar loads)
//  - softmax p staged ONCE in LDS for the 6x258 halo (1.5 softmax/px, was 5;
//    pred VMEM ~24/thread, was 80); |laplacian| stencil reads LDS
//  - per-px window min (exact cutoff 25) + rare exact fallback scan
//  - block reduction -> partial[block]
// ---------------------------------------------------------------------------
__global__ __launch_bounds__(256) void k_main(const float* __restrict__ pred,
                                              const unsigned short* __restrict__ Dt,
                                              float2* __restrict__ partial) {
    int blk  = blockIdx.x;          // b*64 + tile
    int b    = blk >> 6;
    int tile = blk & 63;
    int h0   = tile * TH;
    int w    = threadIdx.x;

    const float* pred_b = pred + (size_t)b * CHW;

    // ---- D register window: rows h0-4 .. h0+7, 4 ch (12 VMEM, 8B-aligned) ----
    float win[TH + 8][NC];
    #pragma unroll
    for (int c = 0; c < NC; ++c) {
        const unsigned short* colp =
            Dt + ((size_t)(b * NC + c) * NW + w) * HP + 4 + h0;
        uint2 v0 = *(const uint2*)(colp - 4);   // rows h0-4 .. h0-1
        uint2 v1 = *(const uint2*)(colp);       // rows h0   .. h0+3
        uint2 v2 = *(const uint2*)(colp + 4);   // rows h0+4 .. h0+7
        unsigned v[6] = {v0.x, v0.y, v1.x, v1.y, v2.x, v2.y};
        #pragma unroll
        for (int k = 0; k < 6; ++k) {
            unsigned a = v[k] & 0xFFFFu;
            unsigned d = v[k] >> 16;
            win[2 * k][c]     = (a > 65025u) ? INFV : (float)a;
            win[2 * k + 1][c] = (d > 65025u) ? INFV : (float)d;
        }
    }

    // ---- stage softmax p for the halo (rows h0-1..h0+4, cols -1..256) ----
    __shared__ float ps[NC][TH + 2][NW + 2];
    for (int pos = threadIdx.x; pos < (TH + 2) * (NW + 2); pos += 256) {
        int row = pos / (NW + 2);          // 0..5
        int col = pos - row * (NW + 2);    // 0..257
        int gy  = h0 - 1 + row;
        int gx  = col - 1;
        float o[NC] = {0.0f, 0.0f, 0.0f, 0.0f};   // zero pad outside image
        if ((unsigned)gy < (unsigned)NH && (unsigned)gx < (unsigned)NW)
            softmax4(pred_b, (gy << 8) + gx, o);
        ps[0][row][col] = o[0];
        ps[1][row][col] = o[1];
        ps[2][row][col] = o[2];
        ps[3][row][col] = o[3];
    }
    __syncthreads();

    float num = 0.0f, den = 0.0f;
    #pragma unroll
    for (int r = 0; r < TH; ++r) {
        int h = h0 + r;
        #pragma unroll
        for (int c = 0; c < NC; ++c) {
            float lap = fabsf(ps[c][r][w + 1] + ps[c][r + 2][w + 1]
                            + ps[c][r + 1][w] + ps[c][r + 1][w + 2]
                            - 4.0f * ps[c][r + 1][w + 1]);

            // window min from registers (all adds exact: ints <= 65041)
            float best = win[r + 4][c];
            #pragma unroll
            for (int dr = 1; dr <= 4; ++dr) {
                float rr = (float)(dr * dr);
                best = fminf(best, rr + win[r + 4 - dr][c]);
                best = fminf(best, rr + win[r + 4 + dr][c]);
            }

            // exact fallback for best > 25 (prob ~1e-8/px; also the
            // empty/absent-channel path). Contiguous u16 reads.
            if (best > 25.0f) {
                const unsigned short* f =
                    Dt + ((size_t)(b * NC + c) * NW + w) * HP + 4;
                for (int r2 = 5; r2 < NH; ++r2) {
                    float rr = (float)(r2 * r2);   // exact int <= 65025
                    if (rr >= best) break;
                    int hu = h - r2, hd = h + r2;
                    if (hu >= 0) {
                        unsigned short u = f[hu];
                        if (u <= 65025) best = fminf(best, rr + (float)u);
                    }
                    if (hd < NH) {
                        unsigned short u = f[hd];
                        if (u <= 65025) best = fminf(best, rr + (float)u);
                    }
                }
            }

            float dv = (best > 1e8f) ? 0.0f : sqrtf(best); // empty-ch mask
            num += lap * dv;
            den += lap;
        }
    }

    #pragma unroll
    for (int off = 32; off > 0; off >>= 1) {
        num += __shfl_down(num, off);
        den += __shfl_down(den, off);
    }
    __shared__ float sn[4], sd[4];
    int lane = threadIdx.x & 63;
    int wvi  = threadIdx.x >> 6;
    if (lane == 0) { sn[wvi] = num; sd[wvi] = den; }
    __syncthreads();
    if (threadIdx.x == 0) {
        partial[blockIdx.x] = make_float2(sn[0] + sn[1] + sn[2] + sn[3],
                                          sd[0] + sd[1] + sd[2] + sd[3]);
    }
}

// ---------------------------------------------------------------------------
// K3: final reduction of partials + divide. One block.
// ---------------------------------------------------------------------------
__global__ __launch_bounds__(256) void k_final(const float2* __restrict__ partial,
                                               float* __restrict__ out) {
    double n = 0.0, d = 0.0;
    for (int i = threadIdx.x; i < MAIN_BLOCKS; i += 256) {
        float2 v = partial[i];
        n += (double)v.x;
        d += (double)v.y;
    }
    #pragma unroll
    for (int off = 32; off > 0; off >>= 1) {
        n += __shfl_down(n, off);
        d += __shfl_down(d, off);
    }
    __shared__ double snd[4], sdd[4];
    int lane = threadIdx.x & 63;
    int wv   = threadIdx.x >> 6;
    if (lane == 0) { snd[wv] = n; sdd[wv] = d; }
    __syncthreads();
    if (threadIdx.x == 0) {
        double nn = snd[0] + snd[1] + snd[2] + snd[3];
        double dd = sdd[0] + sdd[1] + sdd[2] + sdd[3];
        out[0] = (float)(nn / dd);
    }
}

extern "C" void kernel_launch(void* const* d_in, const int* in_sizes, int n_in,
                              void* d_out, int out_size, void* d_ws, size_t ws_size,
                              hipStream_t stream) {
    const float* pred = (const float*)d_in[0];
    const int*   tgt  = (const int*)d_in[1];
    float*       out  = (float*)d_out;

    unsigned short* Dt      = (unsigned short*)d_ws;   // 8*4*256*264*2 ≈ 4.33 MB
    float2*         partial = (float2*)((char*)d_ws
                              + (size_t)NB * NC * NW * HP * sizeof(unsigned short));

    k_edt_w<<<NB * (NH / TH), 256, 0, stream>>>(tgt, Dt);
    k_main <<<MAIN_BLOCKS,    256, 0, stream>>>(pred, Dt, partial);
    k_final<<<1,              256, 0, stream>>>(partial, out);
}

// Round 8
// 24.785 us; speedup vs baseline: 1.2846x; 1.2846x over previous
//
#include <hip/hip_runtime.h>

#define NB 8
#define NC 4
#define NH 256
#define NW 256
#define HW (NH * NW)      // 65536
#define CHW (NC * HW)     // 262144
#define INFV 1e10f
#define TH 4                              // output rows per block
#define MAIN_BLOCKS (NB * (NH / TH))      // 512
#define WR (TH + 8)                       // window rows held in registers (12)

// ---------------------------------------------------------------------------
// K1: EDT pass 1 along W — ballot version (round-6 proven form).
// One block (256 thr) per (b,h). Output u16 squared distance (<= 65025,
// exact) or 65535 = class absent from this row (reference: 1e10).
// Row-major [b][c][h][w]: adjacent threads store adjacent u16 (coalesced).
// ---------------------------------------------------------------------------
__global__ __launch_bounds__(256) void k_edt_w(const int* __restrict__ tgt,
                                               unsigned short* __restrict__ D16) {
    int bh = blockIdx.x;            // b*NH + h
    int i  = threadIdx.x;
    int wv = i >> 6;                // wave id (0..3)
    int ln = i & 63;

    int tv = tgt[(size_t)bh * NW + i];

    __shared__ unsigned long long mk[NC][4];
    #pragma unroll
    for (int c = 0; c < NC; ++c) {
        unsigned long long m = __ballot(tv == c);
        if (ln == 0) mk[c][wv] = m;
    }
    __syncthreads();

    unsigned long long le = (ln == 63) ? ~0ull : ((1ull << (ln + 1)) - 1ull);
    unsigned long long ge = ~0ull << ln;

    unsigned short res[NC];
    #pragma unroll
    for (int c = 0; c < NC; ++c) {
        int jl = -1000;
        #pragma unroll
        for (int k = 0; k < 4; ++k) {
            unsigned long long x = mk[c][k];
            x = (k > wv) ? 0ull : ((k == wv) ? (x & le) : x);
            if (x) jl = k * 64 + 63 - __clzll((long long)x);
        }
        int jr = 1000;
        #pragma unroll
        for (int k = 3; k >= 0; --k) {
            unsigned long long x = mk[c][k];
            x = (k < wv) ? 0ull : ((k == wv) ? (x & ge) : x);
            if (x) jr = k * 64 + __ffsll((unsigned long long)x) - 1;
        }
        int dl = i - jl;
        int dr = jr - i;
        int dd = min(dl, dr);
        res[c] = (dd > 255) ? (unsigned short)65535
                            : (unsigned short)(dd * dd);
    }

    int b = bh >> 8;
    int h = bh & 255;
    size_t o = (size_t)b * CHW + (size_t)h * NW + i;
    D16[o]          = res[0];
    D16[o + HW]     = res[1];
    D16[o + 2 * HW] = res[2];
    D16[o + 3 * HW] = res[3];
}

// ---------------------------------------------------------------------------
// softmax of the 4 channel logits at pixel offset hw of batch-base pred_b.
// ---------------------------------------------------------------------------
__device__ __forceinline__ void softmax4(const float* __restrict__ pred_b,
                                         int hw, float o[NC]) {
    float x0 = pred_b[hw];
    float x1 = pred_b[hw + HW];
    float x2 = pred_b[hw + 2 * HW];
    float x3 = pred_b[hw + 3 * HW];
    float m  = fmaxf(fmaxf(x0, x1), fmaxf(x2, x3));
    float e0 = __expf(x0 - m);
    float e1 = __expf(x1 - m);
    float e2 = __expf(x2 - m);
    float e3 = __expf(x3 - m);
    float inv = 1.0f / (e0 + e1 + e2 + e3);
    o[0] = e0 * inv; o[1] = e1 * inv; o[2] = e2 * inv; o[3] = e3 * inv;
}

// ---------------------------------------------------------------------------
// K2: fused kernel (round-6 structure + LDS softmax staging).
// Block = 256 threads (w) x TH=4 output rows.
//  - D window rows h0-4..h0+7 x 4ch loaded once into registers
//    (48 coalesced u16 loads/thread; each value serves up to 9 outputs)
//  - softmax p staged ONCE in LDS for the 6x258 halo (24 exp/thread vs 80;
//    24 coalesced pred loads vs 80); |laplacian| stencil reads LDS
//  - per-px window min (exact cutoff 25) + rare exact fallback scan
//    (also handles the empty/absent-channel path -> masks to 0)
//  - block reduction -> partial[block]
// ---------------------------------------------------------------------------
__global__ __launch_bounds__(256) void k_main(const float* __restrict__ pred,
                                              const unsigned short* __restrict__ D16,
                                              float2* __restrict__ partial) {
    int blk  = blockIdx.x;          // b*64 + tile
    int b    = blk >> 6;
    int tile = blk & 63;
    int h0   = tile * TH;
    int w    = threadIdx.x;

    const unsigned short* Db = D16 + (size_t)b * CHW + w;
    const float* pred_b = pred + (size_t)b * CHW;

    // ---- D register window (fully unrolled -> static indices) ----
    float win[WR][NC];
    #pragma unroll
    for (int k = 0; k < WR; ++k) {
        int j = h0 - 4 + k;
        bool ok = (unsigned)j < (unsigned)NH;
        #pragma unroll
        for (int c = 0; c < NC; ++c) {
            unsigned short u = ok ? Db[(size_t)c * HW + (j << 8)]
                                  : (unsigned short)65535;
            win[k][c] = (u > 65025) ? INFV : (float)u;
        }
    }

    // ---- stage softmax p for the halo (rows h0-1..h0+4, cols -1..256) ----
    __shared__ float ps[NC][TH + 2][NW + 2];
    for (int pos = threadIdx.x; pos < (TH + 2) * (NW + 2); pos += 256) {
        int row = pos / (NW + 2);          // 0..5
        int col = pos - row * (NW + 2);    // 0..257
        int gy  = h0 - 1 + row;
        int gx  = col - 1;
        float o[NC] = {0.0f, 0.0f, 0.0f, 0.0f};   // zero pad outside image
        if ((unsigned)gy < (unsigned)NH && (unsigned)gx < (unsigned)NW)
            softmax4(pred_b, (gy << 8) + gx, o);
        ps[0][row][col] = o[0];
        ps[1][row][col] = o[1];
        ps[2][row][col] = o[2];
        ps[3][row][col] = o[3];
    }
    __syncthreads();

    float num = 0.0f, den = 0.0f;
    #pragma unroll
    for (int r = 0; r < TH; ++r) {
        int h = h0 + r;
        #pragma unroll
        for (int c = 0; c < NC; ++c) {
            float lap = fabsf(ps[c][r][w + 1] + ps[c][r + 2][w + 1]
                            + ps[c][r + 1][w] + ps[c][r + 1][w + 2]
                            - 4.0f * ps[c][r + 1][w + 1]);

            // window min from registers (all adds exact: ints <= 65041)
            float best = win[r + 4][c];
            #pragma unroll
            for (int dr = 1; dr <= 4; ++dr) {
                float rr = (float)(dr * dr);
                best = fminf(best, rr + win[r + 4 - dr][c]);
                best = fminf(best, rr + win[r + 4 + dr][c]);
            }

            // exact fallback for best > 25 (prob ~1e-10/px with this data;
            // also the empty/absent-channel path). Coalesced u16 reads.
            if (best > 25.0f) {
                const unsigned short* f = Db + (size_t)c * HW;
                for (int r2 = 5; r2 < NH; ++r2) {
                    float rr = (float)(r2 * r2);   // exact int <= 65025
                    if (rr >= best) break;
                    int hu = h - r2, hd = h + r2;
                    if (hu >= 0) {
                        unsigned short u = f[hu << 8];
                        if (u <= 65025) best = fminf(best, rr + (float)u);
                    }
                    if (hd < NH) {
                        unsigned short u = f[hd << 8];
                        if (u <= 65025) best = fminf(best, rr + (float)u);
                    }
                }
            }

            float dv = (best > 1e8f) ? 0.0f : sqrtf(best); // empty-ch mask
            num += lap * dv;
            den += lap;
        }
    }

    #pragma unroll
    for (int off = 32; off > 0; off >>= 1) {
        num += __shfl_down(num, off);
        den += __shfl_down(den, off);
    }
    __shared__ float sn[4], sd[4];
    int lane = threadIdx.x & 63;
    int wvi  = threadIdx.x >> 6;
    if (lane == 0) { sn[wvi] = num; sd[wvi] = den; }
    __syncthreads();
    if (threadIdx.x == 0) {
        partial[blockIdx.x] = make_float2(sn[0] + sn[1] + sn[2] + sn[3],
                                          sd[0] + sd[1] + sd[2] + sd[3]);
    }
}

// ---------------------------------------------------------------------------
// K3: final reduction of partials + divide. One block.
// ---------------------------------------------------------------------------
__global__ __launch_bounds__(256) void k_final(const float2* __restrict__ partial,
                                               float* __restrict__ out) {
    double n = 0.0, d = 0.0;
    for (int i = threadIdx.x; i < MAIN_BLOCKS; i += 256) {
        float2 v = partial[i];
        n += (double)v.x;
        d += (double)v.y;
    }
    #pragma unroll
    for (int off = 32; off > 0; off >>= 1) {
        n += __shfl_down(n, off);
        d += __shfl_down(d, off);
    }
    __shared__ double snd[4], sdd[4];
    int lane = threadIdx.x & 63;
    int wv   = threadIdx.x >> 6;
    if (lane == 0) { snd[wv] = n; sdd[wv] = d; }
    __syncthreads();
    if (threadIdx.x == 0) {
        double nn = snd[0] + snd[1] + snd[2] + snd[3];
        double dd = sdd[0] + sdd[1] + sdd[2] + sdd[3];
        out[0] = (float)(nn / dd);
    }
}

extern "C" void kernel_launch(void* const* d_in, const int* in_sizes, int n_in,
                              void* d_out, int out_size, void* d_ws, size_t ws_size,
                              hipStream_t stream) {
    const float* pred = (const float*)d_in[0];
    const int*   tgt  = (const int*)d_in[1];
    float*       out  = (float*)d_out;

    unsigned short* D16     = (unsigned short*)d_ws;                 // 4 MB
    float2*         partial = (float2*)((char*)d_ws + (size_t)NB * CHW * 2);

    k_edt_w<<<NB * NH,     256, 0, stream>>>(tgt, D16);
    k_main <<<MAIN_BLOCKS, 256, 0, stream>>>(pred, D16, partial);
    k_final<<<1,           256, 0, stream>>>(partial, out);
}